// Round 5
// baseline (4711.061 us; speedup 1.0000x reference)
//
#include <hip/hip_runtime.h>

#define N_VNS 65536
#define N_CNS 32768
#define DV 4
#define NE (N_VNS * DV)   // 262144 edges per graph
#define B 64              // full batch
#define BH 32             // batch columns per pass (fits fp64 msgs in ws)
#define NITER 8

__device__ __forceinline__ double sp_(double y) {   // softplus, stable
    return fmax(y, 0.0) + log1p(exp(-fabs(y)));
}
__device__ __forceinline__ double clipllr(double x) {
    return fmin(fmax(x, -20.0), 20.0);
}
__device__ __forceinline__ double t_of(double m) {  // tanh(m/2), 0 -> 1e-12
    double t = tanh(0.5 * m);
    return (t == 0.0) ? 1e-12 : t;
}

// ---------------------------------------------------------------------------
// Per-CN segment [start,end) from the sorted cn_ids. Empty CNs keep 0,0.
__global__ void rowptr_k(const int* __restrict__ cn_x, const int* __restrict__ cn_z,
                         int* __restrict__ sx, int* __restrict__ ex,
                         int* __restrict__ sz, int* __restrict__ ez) {
    int i = blockIdx.x * blockDim.x + threadIdx.x;
    const int* cn = blockIdx.y ? cn_z : cn_x;
    int* s = blockIdx.y ? sz : sx;
    int* e = blockIdx.y ? ez : ex;
    int c = cn[i];
    if (i == 0 || cn[i - 1] != c) s[c] = i;
    if (i == NE - 1 || cn[i + 1] != c) e[c] = i + 1;
}

// ---------------------------------------------------------------------------
// VN update, both graphs, one batch-half. Thread = (vn, b_local).
// Reads c2v msgs (LLR domain), writes tanh(msg/2) in place. fp64 throughout.
template <bool FIRST>
__global__ void vn_k(const float* __restrict__ llr,
                     double* __restrict__ msg_x, double* __restrict__ msg_z,
                     int half) {
    int tid = blockIdx.x * blockDim.x + threadIdx.x;
    int v = tid >> 5, b = tid & 31;
    long base = (long)v * (DV * BH) + b;

    double mx[DV], mz[DV];
    double sumx = 0.0, sumz = 0.0;
#pragma unroll
    for (int k = 0; k < DV; ++k) {
        if (FIRST) { mx[k] = 0.0; mz[k] = 0.0; }
        else       { mx[k] = msg_x[base + k * BH]; mz[k] = msg_z[base + k * BH]; }
        sumx += mx[k]; sumz += mz[k];
    }
    long li = (long)v * B + half * BH + b;     // global (vn, batch) index
    double lx = clipllr((double)llr[li]);
    double ly = clipllr((double)llr[(long)N_VNS * B + li]);
    double lz = clipllr((double)llr[2L * N_VNS * B + li]);

    double llrx_hx  = sumz + lx;
    double llry_all = sumx + sumz + ly;
    double llrz_hz  = sumx + lz;
    double spx = sp_(-llrx_hx);
    double spz = sp_(-llrz_hz);

#pragma unroll
    for (int k = 0; k < DV; ++k) {
        // graph X: softplus(-llrx_hx) - logaddexp(-llrz_hx, -llry_hx)
        double a  = llrz_hz  - mx[k];
        double c2 = llry_all - mx[k];
        double nmx = spx + fmin(a, c2) - log1p(exp(-fabs(a - c2)));
        msg_x[base + k * BH] = t_of(clipllr(nmx));
        // graph Z
        double az = llrx_hx  - mz[k];
        double cz = llry_all - mz[k];
        double nmz = spz + fmin(az, cz) - log1p(exp(-fabs(az - cz)));
        msg_z[base + k * BH] = t_of(clipllr(nmz));
    }
}

// ---------------------------------------------------------------------------
// CN update, one batch-half. 32 lanes per CN (8 CNs / 256-thread block).
// Gathers tanh-domain msgs via perm_v2c, writes 2*atanh(extrinsic) back to
// the SAME VN-rows (each row belongs to exactly one CN -> in-place safe).
__global__ void cn_k(const int* __restrict__ synd_x, const int* __restrict__ synd_z,
                     const int* __restrict__ pv_x, const int* __restrict__ pv_z,
                     const int* __restrict__ sx, const int* __restrict__ ex,
                     const int* __restrict__ sz, const int* __restrict__ ez,
                     double* __restrict__ msg_x, double* __restrict__ msg_z,
                     int half) {
    const double ACLIP = 1.0 - 1e-7;
    int wid = threadIdx.x >> 5;
    int c = blockIdx.x * 8 + wid;
    int b = threadIdx.x & 31;
    bool gz = (blockIdx.y != 0);
    const int* pv   = gz ? pv_z : pv_x;
    const int* synd = gz ? synd_z : synd_x;
    double* msg     = gz ? msg_z : msg_x;
    int s = (gz ? sz : sx)[c];
    int e = (gz ? ez : ex)[c];

    double prod = 1.0 - 2.0 * (double)synd[c * B + half * BH + b];
    for (int i = s; i < e; ++i) {
        prod *= msg[(long)pv[i] * BH + b];
    }
    for (int i = s; i < e; ++i) {
        long r = (long)pv[i] * BH + b;
        double t = msg[r];                     // tanh value (L2-hot)
        double ext = prod / t;
        ext = (fabs(ext) < 1e-7) ? 0.0 : ext;
        ext = fmin(fmax(ext, -ACLIP), ACLIP);
        msg[r] = 2.0 * atanh(ext);             // back to LLR domain
    }
}

// ---------------------------------------------------------------------------
// Final marginals for one batch-half:
// out[0]=sum_z+lx, out[1]=sum_x+sum_z+ly, out[2]=sum_x+lz
__global__ void final_k(const float* __restrict__ llr,
                        const double* __restrict__ msg_x,
                        const double* __restrict__ msg_z,
                        float* __restrict__ out, int half) {
    int tid = blockIdx.x * blockDim.x + threadIdx.x;
    int v = tid >> 5, b = tid & 31;
    long base = (long)v * (DV * BH) + b;
    double sumx = 0.0, sumz = 0.0;
#pragma unroll
    for (int k = 0; k < DV; ++k) {
        sumx += msg_x[base + k * BH];
        sumz += msg_z[base + k * BH];
    }
    long li = (long)v * B + half * BH + b;
    double lx = clipllr((double)llr[li]);
    double ly = clipllr((double)llr[(long)N_VNS * B + li]);
    double lz = clipllr((double)llr[2L * N_VNS * B + li]);
    out[li]                   = (float)(sumz + lx);
    out[(long)N_VNS * B + li] = (float)(sumx + sumz + ly);
    out[2L * N_VNS * B + li]  = (float)(sumx + lz);
}

// ---------------------------------------------------------------------------
extern "C" void kernel_launch(void* const* d_in, const int* in_sizes, int n_in,
                              void* d_out, int out_size, void* d_ws, size_t ws_size,
                              hipStream_t stream) {
    const float* llr  = (const float*)d_in[0];
    const int* synd_x = (const int*)d_in[1];
    const int* synd_z = (const int*)d_in[2];
    // d_in[3,4]: vn_ids (structurally e>>2, unused)
    const int* cn_x = (const int*)d_in[5];
    const int* cn_z = (const int*)d_in[6];
    const int* pv_x = (const int*)d_in[7];
    const int* pv_z = (const int*)d_in[8];
    // d_in[9,10]: perm_c2v (folded into in-place scatter); d_in[11]: num_iter=8

    // fp64 messages for ONE batch-half: 2 * 262144 * 32 * 8 = 134.22 MB
    // + 0.5 MB rowptr — exactly the footprint proven available in R2.
    double* msg_x = (double*)d_ws;
    double* msg_z = msg_x + (size_t)NE * BH;
    int* sx = (int*)(msg_z + (size_t)NE * BH);
    int* ex = sx + N_CNS;
    int* sz = ex + N_CNS;
    int* ez = sz + N_CNS;

    hipMemsetAsync(sx, 0, 4 * (size_t)N_CNS * sizeof(int), stream);
    rowptr_k<<<dim3(NE / 256, 2), 256, 0, stream>>>(cn_x, cn_z, sx, ex, sz, ez);

    dim3 vn_grid(N_VNS * BH / 256);       // 8192 blocks
    dim3 cn_grid(N_CNS / 8, 2);           // 8 CNs per 256-thread block

    for (int half = 0; half < 2; ++half) {
        vn_k<true><<<vn_grid, 256, 0, stream>>>(llr, msg_x, msg_z, half);
        cn_k<<<cn_grid, 256, 0, stream>>>(synd_x, synd_z, pv_x, pv_z,
                                          sx, ex, sz, ez, msg_x, msg_z, half);
        for (int it = 1; it < NITER; ++it) {
            vn_k<false><<<vn_grid, 256, 0, stream>>>(llr, msg_x, msg_z, half);
            cn_k<<<cn_grid, 256, 0, stream>>>(synd_x, synd_z, pv_x, pv_z,
                                              sx, ex, sz, ez, msg_x, msg_z, half);
        }
        final_k<<<vn_grid, 256, 0, stream>>>(llr, msg_x, msg_z, (float*)d_out, half);
    }
}

// Round 9
// 4138.984 us; speedup vs baseline: 1.1382x; 1.1382x over previous
//
#include <hip/hip_runtime.h>

#define N_VNS 65536
#define N_CNS 32768
#define DV 4
#define NE (N_VNS * DV)   // 262144 edges per graph
#define B 64              // full batch
#define BH 16             // batch columns per pass (4 fp64 buffers fit ws)
#define NQ (B / BH)       // 4 passes
#define NITER 8

// tanh(10.0) correctly rounded; tanh(clip(x,±20)/2) == clamp(tanh(x/2), ±TANH10)
#define TANH10 0.9999999958776927

__device__ __forceinline__ double sp_(double y) {   // softplus, stable
    return fmax(y, 0.0) + log1p(exp(-fabs(y)));
}
__device__ __forceinline__ double clipllr(double x) {
    return fmin(fmax(x, -20.0), 20.0);
}

// ---------------------------------------------------------------------------
// Per-CN segment [start,end) from the sorted cn_ids. Empty CNs keep 0,0.
__global__ void rowptr_k(const int* __restrict__ cn_x, const int* __restrict__ cn_z,
                         int* __restrict__ sx, int* __restrict__ ex,
                         int* __restrict__ sz, int* __restrict__ ez) {
    int i = blockIdx.x * blockDim.x + threadIdx.x;
    const int* cn = blockIdx.y ? cn_z : cn_x;
    int* s = blockIdx.y ? sz : sx;
    int* e = blockIdx.y ? ez : ex;
    int c = cn[i];
    if (i == 0 || cn[i - 1] != c) s[c] = i;
    if (i == NE - 1 || cn[i + 1] != c) e[c] = i + 1;
}

// ---------------------------------------------------------------------------
// VN update, both graphs, one batch-quarter. Thread = (vn, b_local).
// Reads c2v LLR msgs (mL*) for sums and c2v tanh values (t*) for the
// tanh-addition formula; writes new v2c tanh values into t* in place.
//
// Key algebra (fp64-exact rewrites of the reference):
//   nmx = constX - mx[k],  constX = sp(-llrx_hx) + min(llrz_hz,llry_all)
//                                   - log1p(exp(-|llrz_hz-llry_all|))
//   tanh(clip(nmx,±20)/2) = clamp( (tCX - ext_k)/(1 - tCX*ext_k), ±tanh(10) )
//     with tCX = tanh(constX/2), ext_k = tanh(mx[k]/2) (stored by cn_k).
template <bool FIRST>
__global__ void vn_k(const float* __restrict__ llr,
                     const double* __restrict__ mLx, const double* __restrict__ mLz,
                     double* __restrict__ tx, double* __restrict__ tz,
                     int q) {
    int tid = blockIdx.x * blockDim.x + threadIdx.x;
    int v = tid >> 4, b = tid & 15;
    long base = (long)v * (DV * BH) + b;

    double mx[DV], mz[DV], exk[DV], ezk[DV];
    double sumx = 0.0, sumz = 0.0;
#pragma unroll
    for (int k = 0; k < DV; ++k) {
        if (FIRST) { mx[k] = 0.0; mz[k] = 0.0; exk[k] = 0.0; ezk[k] = 0.0; }
        else {
            mx[k] = mLx[base + k * BH];  exk[k] = tx[base + k * BH];
            mz[k] = mLz[base + k * BH];  ezk[k] = tz[base + k * BH];
        }
        sumx += mx[k]; sumz += mz[k];
    }
    long li = (long)v * B + q * BH + b;
    double lx = clipllr((double)llr[li]);
    double ly = clipllr((double)llr[(long)N_VNS * B + li]);
    double lz = clipllr((double)llr[2L * N_VNS * B + li]);

    double llrx_hx  = sumz + lx;
    double llry_all = sumx + sumz + ly;
    double llrz_hz  = sumx + lz;

    // graph X constant and its half-tanh
    double dX = fabs(llrz_hz - llry_all);
    double cX = sp_(-llrx_hx) + fmin(llrz_hz, llry_all) - log1p(exp(-dX));
    double tCX = tanh(0.5 * cX);
    // graph Z
    double dZ = fabs(llrx_hx - llry_all);
    double cZ = sp_(-llrz_hz) + fmin(llrx_hx, llry_all) - log1p(exp(-dZ));
    double tCZ = tanh(0.5 * cZ);

#pragma unroll
    for (int k = 0; k < DV; ++k) {
        double tn = (tCX - exk[k]) / (1.0 - tCX * exk[k]);
        tn = fmin(fmax(tn, -TANH10), TANH10);
        if (tn == 0.0) tn = 1e-12;            // reference's t==0 fixup
        tx[base + k * BH] = tn;

        double tm = (tCZ - ezk[k]) / (1.0 - tCZ * ezk[k]);
        tm = fmin(fmax(tm, -TANH10), TANH10);
        if (tm == 0.0) tm = 1e-12;
        tz[base + k * BH] = tm;
    }
}

// ---------------------------------------------------------------------------
// CN update, one batch-quarter. 16 lanes (batch cols) per CN, 16 CNs/block.
// Gathers v2c tanh values via perm_v2c, forms signed product, writes per-edge
// clipped extrinsic (into t*, consumed by next vn_k's addition formula) AND
// the LLR-domain message 2*atanh(ext) (into mL*, consumed by vn_k's sums).
__global__ void cn_k(const int* __restrict__ synd_x, const int* __restrict__ synd_z,
                     const int* __restrict__ pv_x, const int* __restrict__ pv_z,
                     const int* __restrict__ sx, const int* __restrict__ ex_,
                     const int* __restrict__ sz, const int* __restrict__ ez_,
                     double* __restrict__ mLx, double* __restrict__ mLz,
                     double* __restrict__ tx, double* __restrict__ tz,
                     int q) {
    const double ACLIP = 1.0 - 1e-7;
    int wid = threadIdx.x >> 4;
    int c = blockIdx.x * 16 + wid;
    int b = threadIdx.x & 15;
    bool gz = (blockIdx.y != 0);
    const int* pv   = gz ? pv_z : pv_x;
    const int* synd = gz ? synd_z : synd_x;
    double* t       = gz ? tz : tx;
    double* mL      = gz ? mLz : mLx;
    int s = (gz ? sz : sx)[c];
    int e = (gz ? ez_ : ex_)[c];

    double prod = 1.0 - 2.0 * (double)synd[c * B + q * BH + b];
    for (int i = s; i < e; ++i) {
        prod *= t[(long)pv[i] * BH + b];
    }
    for (int i = s; i < e; ++i) {
        long r = (long)pv[i] * BH + b;
        double tv = t[r];                    // L2-hot re-read
        double e2 = prod / tv;
        e2 = (fabs(e2) < 1e-7) ? 0.0 : e2;
        e2 = fmin(fmax(e2, -ACLIP), ACLIP);
        t[r]  = e2;                          // tanh(msg/2) for next vn_k
        mL[r] = 2.0 * atanh(e2);             // LLR-domain message
    }
}

// ---------------------------------------------------------------------------
// Final marginals for one batch-quarter:
// out[0]=sum_z+lx, out[1]=sum_x+sum_z+ly, out[2]=sum_x+lz
__global__ void final_k(const float* __restrict__ llr,
                        const double* __restrict__ mLx,
                        const double* __restrict__ mLz,
                        float* __restrict__ out, int q) {
    int tid = blockIdx.x * blockDim.x + threadIdx.x;
    int v = tid >> 4, b = tid & 15;
    long base = (long)v * (DV * BH) + b;
    double sumx = 0.0, sumz = 0.0;
#pragma unroll
    for (int k = 0; k < DV; ++k) {
        sumx += mLx[base + k * BH];
        sumz += mLz[base + k * BH];
    }
    long li = (long)v * B + q * BH + b;
    double lx = clipllr((double)llr[li]);
    double ly = clipllr((double)llr[(long)N_VNS * B + li]);
    double lz = clipllr((double)llr[2L * N_VNS * B + li]);
    out[li]                   = (float)(sumz + lx);
    out[(long)N_VNS * B + li] = (float)(sumx + sumz + ly);
    out[2L * N_VNS * B + li]  = (float)(sumx + lz);
}

// ---------------------------------------------------------------------------
extern "C" void kernel_launch(void* const* d_in, const int* in_sizes, int n_in,
                              void* d_out, int out_size, void* d_ws, size_t ws_size,
                              hipStream_t stream) {
    const float* llr  = (const float*)d_in[0];
    const int* synd_x = (const int*)d_in[1];
    const int* synd_z = (const int*)d_in[2];
    // d_in[3,4]: vn_ids (structurally e>>2, unused)
    const int* cn_x = (const int*)d_in[5];
    const int* cn_z = (const int*)d_in[6];
    const int* pv_x = (const int*)d_in[7];
    const int* pv_z = (const int*)d_in[8];
    // d_in[9,10]: perm_c2v (folded into in-place scatter); d_in[11]: num_iter=8

    // 4 fp64 buffers, one batch-quarter each: 4 * 262144*16*8 = 134.22 MB
    // + 0.5 MB rowptr — the footprint proven available in R2/R5.
    double* mLx = (double*)d_ws;                 // LLR c2v messages, graph X
    double* mLz = mLx + (size_t)NE * BH;         // graph Z
    double* tx  = mLz + (size_t)NE * BH;         // tanh-domain values, graph X
    double* tz  = tx  + (size_t)NE * BH;         // graph Z
    int* sx = (int*)(tz + (size_t)NE * BH);
    int* ex = sx + N_CNS;
    int* sz = ex + N_CNS;
    int* ez = sz + N_CNS;

    hipMemsetAsync(sx, 0, 4 * (size_t)N_CNS * sizeof(int), stream);
    rowptr_k<<<dim3(NE / 256, 2), 256, 0, stream>>>(cn_x, cn_z, sx, ex, sz, ez);

    dim3 vn_grid(N_VNS * BH / 256);       // 4096 blocks
    dim3 cn_grid(N_CNS / 16, 2);          // 16 CNs per 256-thread block

    for (int q = 0; q < NQ; ++q) {
        vn_k<true><<<vn_grid, 256, 0, stream>>>(llr, mLx, mLz, tx, tz, q);
        cn_k<<<cn_grid, 256, 0, stream>>>(synd_x, synd_z, pv_x, pv_z,
                                          sx, ex, sz, ez, mLx, mLz, tx, tz, q);
        for (int it = 1; it < NITER; ++it) {
            vn_k<false><<<vn_grid, 256, 0, stream>>>(llr, mLx, mLz, tx, tz, q);
            cn_k<<<cn_grid, 256, 0, stream>>>(synd_x, synd_z, pv_x, pv_z,
                                              sx, ex, sz, ez, mLx, mLz, tx, tz, q);
        }
        final_k<<<vn_grid, 256, 0, stream>>>(llr, mLx, mLz, (float*)d_out, q);
    }
}

// Round 12
// 3466.542 us; speedup vs baseline: 1.3590x; 1.1940x over previous
//
#include <hip/hip_runtime.h>

#define N_VNS 65536
#define N_CNS 32768
#define DV 4
#define NE (N_VNS * DV)   // 262144 edges per graph
#define B 64              // full batch
#define BH 32             // batch columns per pass (2 fp64 buffers fit ws)
#define NQ (B / BH)       // 2 passes
#define NITER 8

// tanh(10.0); tanh(clip(x,±20)/2) == clamp(tanh(x/2), ±TANH10) by monotonicity
#define TANH10 0.9999999958776927

__device__ __forceinline__ double sp_(double y) {   // softplus, stable
    return fmax(y, 0.0) + log1p(exp(-fabs(y)));
}
__device__ __forceinline__ double clipllr(double x) {
    return fmin(fmax(x, -20.0), 20.0);
}

// ---------------------------------------------------------------------------
// Per-CN segment [start,end) from the sorted cn_ids. Empty CNs keep 0,0.
__global__ void rowptr_k(const int* __restrict__ cn_x, const int* __restrict__ cn_z,
                         int* __restrict__ sx, int* __restrict__ ex,
                         int* __restrict__ sz, int* __restrict__ ez) {
    int i = blockIdx.x * blockDim.x + threadIdx.x;
    const int* cn = blockIdx.y ? cn_z : cn_x;
    int* s = blockIdx.y ? sz : sx;
    int* e = blockIdx.y ? ez : ex;
    int c = cn[i];
    if (i == 0 || cn[i - 1] != c) s[c] = i;
    if (i == NE - 1 || cn[i + 1] != c) e[c] = i + 1;
}

// ---------------------------------------------------------------------------
// VN update, both graphs, one batch-half. Thread = (vn, b_local).
// Everything crosses the CN/VN boundary in tanh domain:
//   exk[k] = stored clipped extrinsic = tanh(msg_k/2)   (exact identity,
//            since reference's msg_k = 2*atanh(ext_k))
//   mx[k]  = 2*atanh(exk[k])          (reconstructed LLR for the sums)
//   nmx    = constX - mx[k],  constX = sp(-llrx_hx) + min(llrz_hz,llry_all)
//                                      - log1p(exp(-|llrz_hz-llry_all|))
//   tanh(clip(nmx,±20)/2) = clamp((tCX - exk)/(1 - tCX*exk), ±TANH10)
template <bool FIRST>
__global__ void vn_k(const float* __restrict__ llr,
                     double* __restrict__ tx, double* __restrict__ tz,
                     int q) {
    int tid = blockIdx.x * blockDim.x + threadIdx.x;
    int v = tid >> 5, b = tid & 31;
    long base = (long)v * (DV * BH) + b;

    double exk[DV], ezk[DV];
    double sumx = 0.0, sumz = 0.0;
#pragma unroll
    for (int k = 0; k < DV; ++k) {
        if (FIRST) { exk[k] = 0.0; ezk[k] = 0.0; }
        else {
            exk[k] = tx[base + k * BH];
            ezk[k] = tz[base + k * BH];
            sumx += 2.0 * atanh(exk[k]);
            sumz += 2.0 * atanh(ezk[k]);
        }
    }
    long li = (long)v * B + q * BH + b;
    double lx = clipllr((double)llr[li]);
    double ly = clipllr((double)llr[(long)N_VNS * B + li]);
    double lz = clipllr((double)llr[2L * N_VNS * B + li]);

    double llrx_hx  = sumz + lx;
    double llry_all = sumx + sumz + ly;
    double llrz_hz  = sumx + lz;

    // graph X constant and its half-tanh
    double dX = fabs(llrz_hz - llry_all);
    double cX = sp_(-llrx_hx) + fmin(llrz_hz, llry_all) - log1p(exp(-dX));
    double tCX = tanh(0.5 * cX);
    // graph Z
    double dZ = fabs(llrx_hx - llry_all);
    double cZ = sp_(-llrz_hz) + fmin(llrx_hx, llry_all) - log1p(exp(-dZ));
    double tCZ = tanh(0.5 * cZ);

#pragma unroll
    for (int k = 0; k < DV; ++k) {
        double tn = (tCX - exk[k]) / (1.0 - tCX * exk[k]);
        tn = fmin(fmax(tn, -TANH10), TANH10);
        if (tn == 0.0) tn = 1e-12;            // reference's t==0 fixup
        tx[base + k * BH] = tn;

        double tm = (tCZ - ezk[k]) / (1.0 - tCZ * ezk[k]);
        tm = fmin(fmax(tm, -TANH10), TANH10);
        if (tm == 0.0) tm = 1e-12;
        tz[base + k * BH] = tm;
    }
}

// ---------------------------------------------------------------------------
// CN update, one batch-half. 32 lanes (batch cols) per CN, 8 CNs/block.
// Pure mul/div — no transcendentals. Gathers v2c tanh values via perm_v2c,
// forms signed product, writes the clipped extrinsic back to the SAME rows
// (in-place safe: each VN-row belongs to exactly one CN).
__global__ void cn_k(const int* __restrict__ synd_x, const int* __restrict__ synd_z,
                     const int* __restrict__ pv_x, const int* __restrict__ pv_z,
                     const int* __restrict__ sx, const int* __restrict__ ex_,
                     const int* __restrict__ sz, const int* __restrict__ ez_,
                     double* __restrict__ tx, double* __restrict__ tz,
                     int q) {
    const double ACLIP = 1.0 - 1e-7;
    int wid = threadIdx.x >> 5;
    int c = blockIdx.x * 8 + wid;
    int b = threadIdx.x & 31;
    bool gz = (blockIdx.y != 0);
    const int* pv   = gz ? pv_z : pv_x;
    const int* synd = gz ? synd_z : synd_x;
    double* t       = gz ? tz : tx;
    int s = (gz ? sz : sx)[c];
    int e = (gz ? ez_ : ex_)[c];

    double prod = 1.0 - 2.0 * (double)synd[c * B + q * BH + b];
    for (int i = s; i < e; ++i) {
        prod *= t[(long)pv[i] * BH + b];
    }
    for (int i = s; i < e; ++i) {
        long r = (long)pv[i] * BH + b;
        double tv = t[r];                    // L1/L2-hot re-read
        double e2 = prod / tv;
        e2 = (fabs(e2) < 1e-7) ? 0.0 : e2;
        e2 = fmin(fmax(e2, -ACLIP), ACLIP);
        t[r] = e2;                           // clipped extrinsic (tanh domain)
    }
}

// ---------------------------------------------------------------------------
// Final marginals for one batch-half. Messages are in tanh domain (clipped
// extrinsics); reconstruct LLRs via 2*atanh and sum.
// out[0]=sum_z+lx, out[1]=sum_x+sum_z+ly, out[2]=sum_x+lz
__global__ void final_k(const float* __restrict__ llr,
                        const double* __restrict__ tx,
                        const double* __restrict__ tz,
                        float* __restrict__ out, int q) {
    int tid = blockIdx.x * blockDim.x + threadIdx.x;
    int v = tid >> 5, b = tid & 31;
    long base = (long)v * (DV * BH) + b;
    double sumx = 0.0, sumz = 0.0;
#pragma unroll
    for (int k = 0; k < DV; ++k) {
        sumx += 2.0 * atanh(tx[base + k * BH]);
        sumz += 2.0 * atanh(tz[base + k * BH]);
    }
    long li = (long)v * B + q * BH + b;
    double lx = clipllr((double)llr[li]);
    double ly = clipllr((double)llr[(long)N_VNS * B + li]);
    double lz = clipllr((double)llr[2L * N_VNS * B + li]);
    out[li]                   = (float)(sumz + lx);
    out[(long)N_VNS * B + li] = (float)(sumx + sumz + ly);
    out[2L * N_VNS * B + li]  = (float)(sumx + lz);
}

// ---------------------------------------------------------------------------
extern "C" void kernel_launch(void* const* d_in, const int* in_sizes, int n_in,
                              void* d_out, int out_size, void* d_ws, size_t ws_size,
                              hipStream_t stream) {
    const float* llr  = (const float*)d_in[0];
    const int* synd_x = (const int*)d_in[1];
    const int* synd_z = (const int*)d_in[2];
    // d_in[3,4]: vn_ids (structurally e>>2, unused)
    const int* cn_x = (const int*)d_in[5];
    const int* cn_z = (const int*)d_in[6];
    const int* pv_x = (const int*)d_in[7];
    const int* pv_z = (const int*)d_in[8];
    // d_in[9,10]: perm_c2v (folded into in-place scatter); d_in[11]: num_iter=8

    // 2 fp64 tanh-domain buffers, one batch-half each: 2 * 262144*32*8
    // = 134.22 MB + 0.5 MB rowptr — the footprint proven available since R2.
    double* tx = (double*)d_ws;                  // graph X edge state
    double* tz = tx + (size_t)NE * BH;           // graph Z edge state
    int* sx = (int*)(tz + (size_t)NE * BH);
    int* ex = sx + N_CNS;
    int* sz = ex + N_CNS;
    int* ez = sz + N_CNS;

    hipMemsetAsync(sx, 0, 4 * (size_t)N_CNS * sizeof(int), stream);
    rowptr_k<<<dim3(NE / 256, 2), 256, 0, stream>>>(cn_x, cn_z, sx, ex, sz, ez);

    dim3 vn_grid(N_VNS * BH / 256);       // 8192 blocks
    dim3 cn_grid(N_CNS / 8, 2);           // 8 CNs per 256-thread block

    for (int q = 0; q < NQ; ++q) {
        vn_k<true><<<vn_grid, 256, 0, stream>>>(llr, tx, tz, q);
        cn_k<<<cn_grid, 256, 0, stream>>>(synd_x, synd_z, pv_x, pv_z,
                                          sx, ex, sz, ez, tx, tz, q);
        for (int it = 1; it < NITER; ++it) {
            vn_k<false><<<vn_grid, 256, 0, stream>>>(llr, tx, tz, q);
            cn_k<<<cn_grid, 256, 0, stream>>>(synd_x, synd_z, pv_x, pv_z,
                                              sx, ex, sz, ez, tx, tz, q);
        }
        final_k<<<vn_grid, 256, 0, stream>>>(llr, tx, tz, (float*)d_out, q);
    }
}